// Round 2
// baseline (101.169 us; speedup 1.0000x reference)
//
#include <hip/hip_runtime.h>

#define N_ATOMS 5000
#define N_EDGES 40000
#define N_TRIP  250000
#define NH      4
#define NHID    64
#define NOUT    64
#define NTYPES  108
#define NPAIRS  (NTYPES * NTYPES)
#define EPSV    0.001f
#define PI_F    3.14159265358979323846f

// ---------------------------------------------------------------------------
// Kernel 1: per-edge atomic types + 108x108 per-head key dot-product table
// W[(za*NTYPES+zb)*NH + h] = sum_i key_emb[za][i*NH+h] * key_emb[zb][i*NH+h]
// ---------------------------------------------------------------------------
__global__ void prep_kernel(const float* __restrict__ key_emb,
                            const int* __restrict__ src_idx,
                            const int* __restrict__ dst_idx,
                            const int* __restrict__ atomic_number,
                            float* __restrict__ W,
                            int* __restrict__ za_e,
                            int* __restrict__ zb_e) {
    int tid = blockIdx.x * blockDim.x + threadIdx.x;
    if (tid < N_EDGES) {
        za_e[tid] = atomic_number[src_idx[tid]];
        zb_e[tid] = atomic_number[dst_idx[tid]];
    }
    if (tid < NPAIRS) {
        int za = tid / NTYPES;
        int zb = tid - za * NTYPES;
        const float* ra = key_emb + za * (NHID * NH);
        const float* rb = key_emb + zb * (NHID * NH);
        float acc0 = 0.f, acc1 = 0.f, acc2 = 0.f, acc3 = 0.f;
        #pragma unroll 8
        for (int i = 0; i < NHID; ++i) {
            float4 va = *reinterpret_cast<const float4*>(ra + i * NH);
            float4 vb = *reinterpret_cast<const float4*>(rb + i * NH);
            acc0 += va.x * vb.x;
            acc1 += va.y * vb.y;
            acc2 += va.z * vb.z;
            acc3 += va.w * vb.w;
        }
        float* wp = W + tid * NH;
        wp[0] = acc0; wp[1] = acc1; wp[2] = acc2; wp[3] = acc3;
    }
}

// ---------------------------------------------------------------------------
// Kernel 2: per-triplet spatial symmetry * type-pair weight -> s_edge[e1][h]
// ---------------------------------------------------------------------------
__global__ void trip_kernel(const float* __restrict__ r,
                            const float* __restrict__ dnr,
                            const float* __restrict__ a_p,
                            const float* __restrict__ b_p,
                            const float* __restrict__ c_p,
                            const float* __restrict__ d_p,
                            const int* __restrict__ lg_src,
                            const int* __restrict__ lg_dst,
                            const int* __restrict__ za_e,
                            const int* __restrict__ zb_e,
                            const float* __restrict__ W,
                            float* __restrict__ s_edge,
                            int* __restrict__ cnt_edge) {
    int t = blockIdx.x * blockDim.x + threadIdx.x;
    if (t >= N_TRIP) return;

    int e1 = lg_src[t];
    int e2 = lg_dst[t];

    float ax = r[e1 * 3 + 0];
    float ay = r[e1 * 3 + 1];
    float az = r[e1 * 3 + 2];
    float bx = r[e2 * 3 + 0];
    float by = r[e2 * 3 + 1];
    float bz = r[e2 * 3 + 2];

    // r1 = -r[e1], r2 = r[e2]  -> dot = -(a.b)
    float dot = -(ax * bx + ay * by + az * bz);
    float n1  = sqrtf(ax * ax + ay * ay + az * az);
    float n2  = sqrtf(bx * bx + by * by + bz * bz);
    float cosv = dot / (n1 * n2);
    cosv = fminf(fmaxf(cosv, -1.0f), 1.0f);
    cosv = fminf(fmaxf(cosv, -EPSV), EPSV);
    float theta = acosf(cosv);

    float dn  = dnr[t];
    float dn2 = dn * dn;

    const float* wp = W + (za_e[e1] * NTYPES + zb_e[e2]) * NH;
    float* sp = s_edge + e1 * NH;

    #pragma unroll
    for (int h = 0; h < NH; ++h) {
        float A = a_p[h];
        float B = fmodf(b_p[h], PI_F);
        float C = c_p[h];
        float D = d_p[h];
        float ang = powf((cosf(A * theta + B) + 1.0f) * 0.5f, C);
        float rad = expf(-D * dn2);
        atomicAdd(&sp[h], wp[h] * ang * rad);
    }
    atomicAdd(&cnt_edge[e1], 1);
}

// ---------------------------------------------------------------------------
// Kernel 3: per (edge, out): sum_h v_dst[e][o,h] * mean_edge[e,h] -> accum[atom,o]
// ---------------------------------------------------------------------------
__global__ void edge_kernel(const float* __restrict__ value_emb,
                            const int* __restrict__ src_idx,
                            const int* __restrict__ zb_e,
                            const float* __restrict__ s_edge,
                            const int* __restrict__ cnt_edge,
                            float* __restrict__ accum,
                            int* __restrict__ cntA) {
    int id = blockIdx.x * blockDim.x + threadIdx.x;
    if (id >= N_EDGES * NOUT) return;
    int e = id >> 6;
    int o = id & 63;

    int cnt = cnt_edge[e];
    float inv = 1.0f / (float)(cnt > 1 ? cnt : 1);
    const float* sp = s_edge + e * NH;
    float m0 = sp[0] * inv, m1 = sp[1] * inv, m2 = sp[2] * inv, m3 = sp[3] * inv;

    int zb = zb_e[e];
    float4 v = *reinterpret_cast<const float4*>(value_emb + zb * (NOUT * NH) + o * NH);
    float val = v.x * m0 + v.y * m1 + v.z * m2 + v.w * m3;

    int n = src_idx[e];
    atomicAdd(&accum[n * NOUT + o], val);
    if (o == 0) atomicAdd(&cntA[n], 1);
}

// ---------------------------------------------------------------------------
// Kernel 4: out[n,o] = accum[n,o] / max(cntA[n],1)
// ---------------------------------------------------------------------------
__global__ void final_kernel(const float* __restrict__ accum,
                             const int* __restrict__ cntA,
                             float* __restrict__ out) {
    int id = blockIdx.x * blockDim.x + threadIdx.x;
    if (id >= N_ATOMS * NOUT) return;
    int n = id >> 6;
    int c = cntA[n];
    float inv = 1.0f / (float)(c > 1 ? c : 1);
    out[id] = accum[id] * inv;
}

extern "C" void kernel_launch(void* const* d_in, const int* in_sizes, int n_in,
                              void* d_out, int out_size, void* d_ws, size_t ws_size,
                              hipStream_t stream) {
    const float* r         = (const float*)d_in[0];
    const float* dnr       = (const float*)d_in[1];
    const float* key_emb   = (const float*)d_in[2];
    const float* value_emb = (const float*)d_in[3];
    const float* a_p       = (const float*)d_in[4];
    const float* b_p       = (const float*)d_in[5];
    const float* c_p       = (const float*)d_in[6];
    const float* d_p       = (const float*)d_in[7];
    const int* src_idx   = (const int*)d_in[8];
    const int* dst_idx   = (const int*)d_in[9];
    const int* lg_src    = (const int*)d_in[10];
    const int* lg_dst    = (const int*)d_in[11];
    const int* atomic_number = (const int*)d_in[12];
    float* out = (float*)d_out;

    char* ws = (char*)d_ws;
    size_t off = 0;
    auto take = [&](size_t bytes) -> char* {
        char* p = ws + off;
        off = (off + bytes + 255) & ~(size_t)255;
        return p;
    };
    float* W        = (float*)take(NPAIRS * NH * sizeof(float));
    int*   za_e     = (int*)  take(N_EDGES * sizeof(int));
    int*   zb_e     = (int*)  take(N_EDGES * sizeof(int));
    char*  zero_beg = ws + off;                       // everything below is accumulated into
    float* s_edge   = (float*)take(N_EDGES * NH * sizeof(float));
    int*   cnt_edge = (int*)  take(N_EDGES * sizeof(int));
    float* accum    = (float*)take(N_ATOMS * NOUT * sizeof(float));
    int*   cntA     = (int*)  take(N_ATOMS * sizeof(int));
    size_t zero_len = (size_t)((ws + off) - zero_beg);

    hipMemsetAsync(zero_beg, 0, zero_len, stream);

    {   // prep: covers both N_EDGES and NPAIRS
        int n = (N_EDGES > NPAIRS ? N_EDGES : NPAIRS);
        prep_kernel<<<(n + 255) / 256, 256, 0, stream>>>(
            key_emb, src_idx, dst_idx, atomic_number, W, za_e, zb_e);
    }
    trip_kernel<<<(N_TRIP + 255) / 256, 256, 0, stream>>>(
        r, dnr, a_p, b_p, c_p, d_p, lg_src, lg_dst, za_e, zb_e, W, s_edge, cnt_edge);
    edge_kernel<<<(N_EDGES * NOUT + 255) / 256, 256, 0, stream>>>(
        value_emb, src_idx, zb_e, s_edge, cnt_edge, accum, cntA);
    final_kernel<<<(N_ATOMS * NOUT + 255) / 256, 256, 0, stream>>>(
        accum, cntA, out);
}